// Round 4
// baseline (206.691 us; speedup 1.0000x reference)
//
#include <hip/hip_runtime.h>

// VectorQuantizer via f16-split-3 MFMA (Markidis fp32 emulation):
//   x = hi + lo*2^-11,  hi = f16(x), lo = f16((x-hi)*2048)
//   dot = [hi.hi] + ([hi.lo] + [lo.hi]) * 2^-11
// argmin_k ||z_hat - w_hat_k|| == argmax_k <z, w_hat_k>  -> only codebook normalized.
//
// R4: fragment-order LDS (conflict-free, R3) + double-buffered global_load_lds
//   prefetch distance 1 (hides DMA latency under MFMA phase, single barrier/kt).
//   BK=32: buffer = 4 planes x 8 units x 512 f16 = 32 KB; x2 bufs = 64 KB.

typedef _Float16 half8 __attribute__((ext_vector_type(8)));
typedef float floatx4 __attribute__((ext_vector_type(4)));

#define C_DIM 256
#define K_CODES 1024
#define HW 1024
#define NPIX 32768
#define LO_SCALE 2048.0f
#define LO_INV   (1.0f/2048.0f)

#define GLOAD_LDS16(g, l) __builtin_amdgcn_global_load_lds(                    \
    (const __attribute__((address_space(1))) unsigned int*)(g),                \
    (__attribute__((address_space(3))) unsigned int*)(l), 16, 0, 0)

// ---------------- kernel 1: normalize codebook + f16 split ------------------
__global__ __launch_bounds__(256) void vq_norm_w(const float* __restrict__ w,
                                                 float* __restrict__ w_n,
                                                 _Float16* __restrict__ wh,
                                                 _Float16* __restrict__ wl) {
    const int row = blockIdx.x;        // 0..1023
    const int t   = threadIdx.x;       // 0..255
    float x = w[row * C_DIM + t];
    float s = x * x;
    #pragma unroll
    for (int off = 32; off > 0; off >>= 1) s += __shfl_down(s, off, 64);
    __shared__ float wsum[4];
    if ((t & 63) == 0) wsum[t >> 6] = s;
    __syncthreads();
    float tot = wsum[0] + wsum[1] + wsum[2] + wsum[3];
    float inv = 1.0f / fmaxf(sqrtf(tot), 1e-12f);
    float y = x * inv;
    w_n[row * C_DIM + t] = y;
    _Float16 hi = (_Float16)y;
    wh[row * C_DIM + t] = hi;
    wl[row * C_DIM + t] = (_Float16)((y - (float)hi) * LO_SCALE);
}

// ---------------- kernel 2: transpose + f16-split z -------------------------
// z [32][256][1024] -> zh/zl [32768 pixels][256 c]
__global__ __launch_bounds__(256) void vq_split_z(const float* __restrict__ z,
                                                  _Float16* __restrict__ zh,
                                                  _Float16* __restrict__ zl) {
    __shared__ float tile[64][65];
    const int t  = threadIdx.x;
    const int pt = blockIdx.x;         // 16 pixel tiles (of 64)
    const int ct = blockIdx.y;         // 4 channel tiles (of 64)
    const int b  = blockIdx.z;         // 32 batches
    const float* zb = z + ((size_t)b * C_DIM + ct * 64) * HW + pt * 64;
    const int rr = t >> 4, pp = (t & 15) * 4;
    #pragma unroll
    for (int pass = 0; pass < 4; pass++) {
        float4 v = *(const float4*)(zb + (size_t)(pass * 16 + rr) * HW + pp);
        *(float4*)&tile[pass * 16 + rr][pp] = v;
    }
    __syncthreads();
    const int pl = t >> 2;
    const size_t pix = (size_t)b * HW + pt * 64 + pl;
    #pragma unroll
    for (int pass = 0; pass < 2; pass++) {
        const int c0 = ((t & 3) + 4 * pass) * 8;
        half8 hi, lo;
        #pragma unroll
        for (int j = 0; j < 8; j++) {
            float x = tile[c0 + j][pl];
            _Float16 h = (_Float16)x;
            hi[j] = h;
            lo[j] = (_Float16)((x - (float)h) * LO_SCALE);
        }
        *(half8*)(zh + pix * C_DIM + ct * 64 + c0) = hi;
        *(half8*)(zl + pix * C_DIM + ct * 64 + c0) = lo;
    }
}

// ---------------- kernel 3: MFMA GEMM + fused argmax ------------------------
// grid (256 m-tiles, 8 n-tiles), 256 thr = 4 waves in 2x2; wave tile 64x64.
// BK=32, 8 kt iterations, double-buffered DMA prefetch (distance 1).
__global__ __launch_bounds__(256, 2) void vq_gemm(
        const _Float16* __restrict__ zh, const _Float16* __restrict__ zl,
        const _Float16* __restrict__ wh, const _Float16* __restrict__ wl,
        float* __restrict__ cand_val, int* __restrict__ cand_idx) {
    // [buf][plane 0=Ah 1=Al 2=Bh 3=Bl][8 units x 512 f16]; unit u = rows u*16..+15
    __shared__ _Float16 lds[2][4][4096];    // 64 KB
    __shared__ float red_v[128][2];
    __shared__ int   red_i[128][2];

    const int tid  = threadIdx.x;
    const int lane = tid & 63, wave = tid >> 6;
    const int wm = wave >> 1, wn = wave & 1;
    const int quad = lane >> 4, l15 = lane & 15;
    const int m0 = blockIdx.x * 128, n0 = blockIdx.y * 128;

    // wave w stages plane w: per-lane global base (row = l15, col = quad*8)
    const _Float16* psrc = (wave == 0) ? zh : (wave == 1) ? zl
                         : (wave == 2) ? wh : wl;
    const int row0 = (wave < 2) ? m0 : n0;
    const _Float16* gbase = psrc + (size_t)(row0 + l15) * C_DIM + quad * 8;

#define STAGE(kt, b) do {                                                      \
        const _Float16* g_ = gbase + (kt) * 32;                                \
        _Float16* l_ = &lds[b][wave][0];                                       \
        _Pragma("unroll")                                                      \
        for (int u_ = 0; u_ < 8; u_++)                                         \
            GLOAD_LDS16(g_ + u_ * (16 * C_DIM), l_ + u_ * 512);                \
    } while (0)

    STAGE(0, 0);                        // prologue: only exposed DMA latency

    floatx4 acc_h[4][4], acc_x[4][4];
    #pragma unroll
    for (int i = 0; i < 4; i++)
        #pragma unroll
        for (int j = 0; j < 4; j++) {
            acc_h[i][j] = (floatx4){0.f, 0.f, 0.f, 0.f};
            acc_x[i][j] = (floatx4){0.f, 0.f, 0.f, 0.f};
        }

    const int afrag = wm * 4, bfrag = wn * 4;

    for (int kt = 0; kt < 8; kt++) {
        __syncthreads();                // drains vmcnt -> buf[kt&1] ready;
                                        // also: prior readers of buf[(kt+1)&1] done
        if (kt + 1 < 8) STAGE(kt + 1, (kt + 1) & 1);   // hidden under compute below
        const int cb = kt & 1;
        half8 ah[4], al[4], bh[4], bl[4];
        #pragma unroll
        for (int i = 0; i < 4; i++) {
            ah[i] = *(const half8*)&lds[cb][0][(afrag + i) * 512 + lane * 8];
            al[i] = *(const half8*)&lds[cb][1][(afrag + i) * 512 + lane * 8];
            bh[i] = *(const half8*)&lds[cb][2][(bfrag + i) * 512 + lane * 8];
            bl[i] = *(const half8*)&lds[cb][3][(bfrag + i) * 512 + lane * 8];
        }
        #pragma unroll
        for (int mi = 0; mi < 4; mi++)
            #pragma unroll
            for (int ni = 0; ni < 4; ni++) {
                acc_h[mi][ni] = __builtin_amdgcn_mfma_f32_16x16x32_f16(ah[mi], bh[ni], acc_h[mi][ni], 0, 0, 0);
                acc_x[mi][ni] = __builtin_amdgcn_mfma_f32_16x16x32_f16(ah[mi], bl[ni], acc_x[mi][ni], 0, 0, 0);
                acc_x[mi][ni] = __builtin_amdgcn_mfma_f32_16x16x32_f16(al[mi], bh[ni], acc_x[mi][ni], 0, 0, 0);
            }
    }

    // epilogue: combine hi/lo, per-lane best over ni, shfl-reduce over quad's 16 lanes
    #pragma unroll
    for (int mi = 0; mi < 4; mi++) {
        #pragma unroll
        for (int r = 0; r < 4; r++) {
            float bv = -__builtin_inff();
            int   bi = 0x7fffffff;
            #pragma unroll
            for (int ni = 0; ni < 4; ni++) {
                float v = acc_h[mi][ni][r] + acc_x[mi][ni][r] * LO_INV;
                int  ci = n0 + wn * 64 + ni * 16 + l15;
                if (v > bv || (v == bv && ci < bi)) { bv = v; bi = ci; }
            }
            #pragma unroll
            for (int mk = 8; mk; mk >>= 1) {
                float ov = __shfl_xor(bv, mk, 16);
                int   oi = __shfl_xor(bi, mk, 16);
                if (ov > bv || (ov == bv && oi < bi)) { bv = ov; bi = oi; }
            }
            if (l15 == 0) {
                int row = wm * 64 + mi * 16 + quad * 4 + r;  // C/D: row=(lane>>4)*4+reg
                red_v[row][wn] = bv;
                red_i[row][wn] = bi;
            }
        }
    }
    __syncthreads();
    if (tid < 128) {
        float bv = red_v[tid][0]; int bi = red_i[tid][0];
        float v2 = red_v[tid][1]; int i2 = red_i[tid][1];
        if (v2 > bv || (v2 == bv && i2 < bi)) { bv = v2; bi = i2; }
        const int pix = m0 + tid;
        cand_val[(size_t)pix * 8 + blockIdx.y] = bv;
        cand_idx[(size_t)pix * 8 + blockIdx.y] = bi;
    }
#undef STAGE
}

// ---------------- kernel 4: reduce 8 candidates + gather --------------------
__global__ __launch_bounds__(256) void vq_finalize(
        const float* __restrict__ cand_val,
        const int*   __restrict__ cand_idx,
        const float* __restrict__ w_n,
        float* __restrict__ zq,          // [32][256][1024]
        float* __restrict__ idx_out) {   // [32768] as float
    const int n = blockIdx.x * 256 + threadIdx.x;
    const size_t base = (size_t)n * 8;
    float bv = cand_val[base];
    int   bi = cand_idx[base];
    #pragma unroll
    for (int t = 1; t < 8; t++) {
        float v = cand_val[base + t];
        int   c = cand_idx[base + t];
        if (v > bv || (v == bv && c < bi)) { bv = v; bi = c; }
    }
    idx_out[n] = (float)bi;
    const int b = n >> 10;
    const int p = n & 1023;
    float* zqb = zq + (size_t)b * (C_DIM * HW) + p;
    const float* wr = w_n + (size_t)bi * C_DIM;
    #pragma unroll 4
    for (int c = 0; c < C_DIM; c += 4) {
        float4 wv = *(const float4*)(wr + c);
        zqb[(size_t)(c + 0) * HW] = wv.x;
        zqb[(size_t)(c + 1) * HW] = wv.y;
        zqb[(size_t)(c + 2) * HW] = wv.z;
        zqb[(size_t)(c + 3) * HW] = wv.w;
    }
}

// ---------------- launcher --------------------------------------------------
extern "C" void kernel_launch(void* const* d_in, const int* in_sizes, int n_in,
                              void* d_out, int out_size, void* d_ws, size_t ws_size,
                              hipStream_t stream) {
    const float* z = (const float*)d_in[0];   // 32*256*32*32
    const float* w = (const float*)d_in[1];   // 1024*256
    float* out     = (float*)d_out;           // z_q (8388608) ++ indices (32768)

    char* ws = (char*)d_ws;
    float*    w_n  = (float*)(ws);                       //  0     .. 1 MB
    _Float16* wh   = (_Float16*)(ws + (1u << 20));       //  1 MB  .. 1.5 MB
    _Float16* wl   = (_Float16*)(ws + (3u << 19));       //  1.5   .. 2 MB
    _Float16* zh   = (_Float16*)(ws + (2u << 20));       //  2 MB  .. 18 MB
    _Float16* zl   = (_Float16*)(ws + 18874368u);        // 18 MB  .. 34 MB
    float*    cval = (float*)(ws + 35651584u);           // 34 MB  .. 35 MB
    int*      cidx = (int*)(ws + 36700160u);             // 35 MB  .. 36 MB

    vq_norm_w<<<K_CODES, 256, 0, stream>>>(w, w_n, wh, wl);
    vq_split_z<<<dim3(16, 4, 32), 256, 0, stream>>>(z, zh, zl);
    vq_gemm<<<dim3(NPIX / 128, K_CODES / 128), 256, 0, stream>>>(zh, zl, wh, wl, cval, cidx);
    vq_finalize<<<NPIX / 256, 256, 0, stream>>>(cval, cidx, w_n, out, out + 8388608);
}

// Round 5
// 189.823 us; speedup vs baseline: 1.0889x; 1.0889x over previous
//
#include <hip/hip_runtime.h>

// VectorQuantizer via f16-split-3 MFMA (Markidis fp32 emulation), single-chain:
//   wh = f16(16*w_hat), wl = f16(16*w_hat - wh)   (uniform x16: argmax-invariant)
//   zh = f16(4*z),      zl = f16(4*z - zh)        (uniform x4:  argmax-invariant)
//   dot64 = hh + hl + lh  (single f32 accumulator chain; ll ~2^-22 rel, dropped)
// argmin_k ||z_hat - w_hat_k|| == argmax_k <z, w_hat_k>  -> only codebook normalized.
//
// R5: 64-AGPR single chain + 32KB single-buffer LDS -> ~4 blocks/CU; block
//     stagger hides DMA drains (m97/m114 mechanism). Coalesced finalize.

typedef _Float16 half8 __attribute__((ext_vector_type(8)));
typedef float floatx4 __attribute__((ext_vector_type(4)));

#define C_DIM 256
#define K_CODES 1024
#define HW 1024
#define NPIX 32768

#define GLOAD_LDS16(g, l) __builtin_amdgcn_global_load_lds(                    \
    (const __attribute__((address_space(1))) unsigned int*)(g),                \
    (__attribute__((address_space(3))) unsigned int*)(l), 16, 0, 0)

// ---------------- kernel 1: normalize codebook + scaled f16 split -----------
__global__ __launch_bounds__(256) void vq_norm_w(const float* __restrict__ w,
                                                 float* __restrict__ w_nT,
                                                 _Float16* __restrict__ wh,
                                                 _Float16* __restrict__ wl) {
    const int row = blockIdx.x;        // 0..1023
    const int t   = threadIdx.x;       // 0..255
    float x = w[row * C_DIM + t];
    float s = x * x;
    #pragma unroll
    for (int off = 32; off > 0; off >>= 1) s += __shfl_down(s, off, 64);
    __shared__ float wsum[4];
    if ((t & 63) == 0) wsum[t >> 6] = s;
    __syncthreads();
    float tot = wsum[0] + wsum[1] + wsum[2] + wsum[3];
    float inv = 1.0f / fmaxf(sqrtf(tot), 1e-12f);
    float y = x * inv;
    w_nT[t * K_CODES + row] = y;       // transposed for finalize's L1-row gather
    float ys = 16.0f * y;
    _Float16 hi = (_Float16)ys;
    wh[row * C_DIM + t] = hi;
    wl[row * C_DIM + t] = (_Float16)(ys - (float)hi);
}

// ---------------- kernel 2: transpose + scaled f16-split z ------------------
// z [32][256][1024] -> zh/zl [32768 pixels][256 c]
__global__ __launch_bounds__(256) void vq_split_z(const float* __restrict__ z,
                                                  _Float16* __restrict__ zh,
                                                  _Float16* __restrict__ zl) {
    __shared__ float tile[64][65];
    const int t  = threadIdx.x;
    const int pt = blockIdx.x;         // 16 pixel tiles (of 64)
    const int ct = blockIdx.y;         // 4 channel tiles (of 64)
    const int b  = blockIdx.z;         // 32 batches
    const float* zb = z + ((size_t)b * C_DIM + ct * 64) * HW + pt * 64;
    const int rr = t >> 4, pp = (t & 15) * 4;
    #pragma unroll
    for (int pass = 0; pass < 4; pass++) {
        float4 v = *(const float4*)(zb + (size_t)(pass * 16 + rr) * HW + pp);
        *(float4*)&tile[pass * 16 + rr][pp] = v;
    }
    __syncthreads();
    const int pl = t >> 2;
    const size_t pix = (size_t)b * HW + pt * 64 + pl;
    #pragma unroll
    for (int pass = 0; pass < 2; pass++) {
        const int c0 = ((t & 3) + 4 * pass) * 8;
        half8 hi, lo;
        #pragma unroll
        for (int j = 0; j < 8; j++) {
            float x = 4.0f * tile[c0 + j][pl];
            _Float16 h = (_Float16)x;
            hi[j] = h;
            lo[j] = (_Float16)(x - (float)h);
        }
        *(half8*)(zh + pix * C_DIM + ct * 64 + c0) = hi;
        *(half8*)(zl + pix * C_DIM + ct * 64 + c0) = lo;
    }
}

// ---------------- kernel 3: MFMA GEMM + fused argmax ------------------------
// grid (256 m-tiles, 8 n-tiles), 256 thr = 4 waves in 2x2; wave tile 64x64.
// BK=32, 8 kt, single 32KB fragment-order buffer staged by global_load_lds.
__global__ __launch_bounds__(256, 4) void vq_gemm(
        const _Float16* __restrict__ zh, const _Float16* __restrict__ zl,
        const _Float16* __restrict__ wh, const _Float16* __restrict__ wl,
        float* __restrict__ cand_val, int* __restrict__ cand_idx) {
    // plane 0=Ah 1=Al 2=Bh 3=Bl; each 8 units x 512 f16; unit u = rows u*16..+15
    __shared__ _Float16 lds[4][4096];       // 32 KB
    __shared__ float red_v[128][2];
    __shared__ int   red_i[128][2];

    const int tid  = threadIdx.x;
    const int lane = tid & 63, wave = tid >> 6;
    const int wm = wave >> 1, wn = wave & 1;
    const int quad = lane >> 4, l15 = lane & 15;
    const int m0 = blockIdx.x * 128, n0 = blockIdx.y * 128;

    // wave w stages plane w: per-lane global base (row = l15, col = quad*8)
    const _Float16* psrc = (wave == 0) ? zh : (wave == 1) ? zl
                         : (wave == 2) ? wh : wl;
    const int row0 = (wave < 2) ? m0 : n0;
    const _Float16* gbase = psrc + (size_t)(row0 + l15) * C_DIM + quad * 8;
    _Float16* ldsw = &lds[wave][0];

    floatx4 acc[4][4];
    #pragma unroll
    for (int i = 0; i < 4; i++)
        #pragma unroll
        for (int j = 0; j < 4; j++) acc[i][j] = (floatx4){0.f, 0.f, 0.f, 0.f};

    const int afrag = wm * 4, bfrag = wn * 4;

    for (int kt = 0; kt < 8; kt++) {
        __syncthreads();                 // prior iter's frag reads done
        const _Float16* g = gbase + kt * 32;
        #pragma unroll
        for (int u = 0; u < 8; u++)      // unit u = rows u*16..+15
            GLOAD_LDS16(g + u * (16 * C_DIM), ldsw + u * 512);
        __syncthreads();                 // vmcnt drain -> DMA data visible

        half8 ah[4], al[4], bh[4], bl[4];
        #pragma unroll
        for (int i = 0; i < 4; i++) {
            ah[i] = *(const half8*)&lds[0][(afrag + i) * 512 + lane * 8];
            al[i] = *(const half8*)&lds[1][(afrag + i) * 512 + lane * 8];
            bh[i] = *(const half8*)&lds[2][(bfrag + i) * 512 + lane * 8];
            bl[i] = *(const half8*)&lds[3][(bfrag + i) * 512 + lane * 8];
        }
        #pragma unroll
        for (int mi = 0; mi < 4; mi++)
            #pragma unroll
            for (int ni = 0; ni < 4; ni++) {
                acc[mi][ni] = __builtin_amdgcn_mfma_f32_16x16x32_f16(ah[mi], bh[ni], acc[mi][ni], 0, 0, 0);
                acc[mi][ni] = __builtin_amdgcn_mfma_f32_16x16x32_f16(ah[mi], bl[ni], acc[mi][ni], 0, 0, 0);
                acc[mi][ni] = __builtin_amdgcn_mfma_f32_16x16x32_f16(al[mi], bh[ni], acc[mi][ni], 0, 0, 0);
            }
    }

    // epilogue: per-lane best over ni, shfl-reduce over quad's 16 lanes
    #pragma unroll
    for (int mi = 0; mi < 4; mi++) {
        #pragma unroll
        for (int r = 0; r < 4; r++) {
            float bv = -__builtin_inff();
            int   bi = 0x7fffffff;
            #pragma unroll
            for (int ni = 0; ni < 4; ni++) {
                float v = acc[mi][ni][r];
                int  ci = n0 + wn * 64 + ni * 16 + l15;
                if (v > bv || (v == bv && ci < bi)) { bv = v; bi = ci; }
            }
            #pragma unroll
            for (int mk = 8; mk; mk >>= 1) {
                float ov = __shfl_xor(bv, mk, 16);
                int   oi = __shfl_xor(bi, mk, 16);
                if (ov > bv || (ov == bv && oi < bi)) { bv = ov; bi = oi; }
            }
            if (l15 == 0) {
                int row = wm * 64 + mi * 16 + quad * 4 + r;  // C/D: row=(lane>>4)*4+reg
                red_v[row][wn] = bv;
                red_i[row][wn] = bi;
            }
        }
    }
    __syncthreads();
    if (tid < 128) {
        float bv = red_v[tid][0]; int bi = red_i[tid][0];
        float v2 = red_v[tid][1]; int i2 = red_i[tid][1];
        if (v2 > bv || (v2 == bv && i2 < bi)) { bv = v2; bi = i2; }
        const int pix = m0 + tid;
        cand_val[(size_t)pix * 8 + blockIdx.y] = bv;
        cand_idx[(size_t)pix * 8 + blockIdx.y] = bi;
    }
}

// ---------------- kernel 4: reduce candidates + coalesced gather ------------
// grid (32 batches, 8 channel-groups), 256 thr. Coalesced 1KB z_q stores;
// codebook gathered from w_nT so each c-iteration hits one 4KB L1-resident row.
__global__ __launch_bounds__(256) void vq_finalize(
        const float* __restrict__ cand_val,
        const int*   __restrict__ cand_idx,
        const float* __restrict__ w_nT,  // [256][1024]
        float* __restrict__ zq,          // [32][256][1024]
        float* __restrict__ idx_out) {   // [32768] as float
    __shared__ int idx_s[1024];
    const int t  = threadIdx.x;
    const int b  = blockIdx.x;
    const int cg = blockIdx.y;           // channels cg*32 .. +31
    #pragma unroll
    for (int q = 0; q < 4; q++) {
        const int p = q * 256 + t;
        const int n = b * 1024 + p;
        const size_t base = (size_t)n * 8;
        float bv = cand_val[base]; int bi = cand_idx[base];
        #pragma unroll
        for (int j = 1; j < 8; j++) {
            float v = cand_val[base + j];
            int   c = cand_idx[base + j];
            if (v > bv || (v == bv && c < bi)) { bv = v; bi = c; }
        }
        idx_s[p] = bi;
        if (cg == 0) idx_out[n] = (float)bi;
    }
    __syncthreads();
    float* zqb = zq + (size_t)b * (C_DIM * HW);
    for (int c = 0; c < 32; c++) {
        const int ch = cg * 32 + c;
        const float* wrow = w_nT + (size_t)ch * K_CODES;
        #pragma unroll
        for (int q = 0; q < 4; q++) {
            const int p = q * 256 + t;
            zqb[(size_t)ch * HW + p] = wrow[idx_s[p]];
        }
    }
}

// ---------------- launcher --------------------------------------------------
extern "C" void kernel_launch(void* const* d_in, const int* in_sizes, int n_in,
                              void* d_out, int out_size, void* d_ws, size_t ws_size,
                              hipStream_t stream) {
    const float* z = (const float*)d_in[0];   // 32*256*32*32
    const float* w = (const float*)d_in[1];   // 1024*256
    float* out     = (float*)d_out;           // z_q (8388608) ++ indices (32768)

    char* ws = (char*)d_ws;
    float*    w_nT = (float*)(ws);                       //  0     .. 1 MB
    _Float16* wh   = (_Float16*)(ws + (1u << 20));       //  1 MB  .. 1.5 MB
    _Float16* wl   = (_Float16*)(ws + (3u << 19));       //  1.5   .. 2 MB
    _Float16* zh   = (_Float16*)(ws + (2u << 20));       //  2 MB  .. 18 MB
    _Float16* zl   = (_Float16*)(ws + 18874368u);        // 18 MB  .. 34 MB
    float*    cval = (float*)(ws + 35651584u);           // 34 MB  .. 35 MB
    int*      cidx = (int*)(ws + 36700160u);             // 35 MB  .. 36 MB

    vq_norm_w<<<K_CODES, 256, 0, stream>>>(w, w_nT, wh, wl);
    vq_split_z<<<dim3(16, 4, 32), 256, 0, stream>>>(z, zh, zl);
    vq_gemm<<<dim3(NPIX / 128, K_CODES / 128), 256, 0, stream>>>(zh, zl, wh, wl, cval, cidx);
    vq_finalize<<<dim3(32, 8), 256, 0, stream>>>(cval, cidx, w_nT, out, out + 8388608);
}

// Round 7
// 175.425 us; speedup vs baseline: 1.1782x; 1.0821x over previous
//
#include <hip/hip_runtime.h>

// VectorQuantizer, fused: gemm reads z directly (transpose+f16-split in-kernel).
//   wh = f16(16*w_hat), wl = f16(16*w_hat - wh)   (uniform x16: argmax-invariant)
//   zh = f16(4*z),      zl = f16(4*z - zh)        (uniform x4:  argmax-invariant)
//   dot64 = hh + hl + lh  (single f32 accumulator chain; ll ~2^-22 rel, dropped)
// argmin_k ||z_hat - w_hat_k|| == argmax_k <z, w_hat_k>  -> only codebook normalized.
//
// R6b: same as R6, typedef fixed (floatx4/floatv4).
//   A path: coalesced fp32 loads from z -> register split -> ds_write_b64 into
//   fragment-order LDS (unit stride 520 f16 to spread banks).
//   B path: global_load_lds(16B) fragment-order DMA (R5-proven), 2 planes.

typedef _Float16 half8 __attribute__((ext_vector_type(8)));
typedef _Float16 half4 __attribute__((ext_vector_type(4)));
typedef float    floatx4 __attribute__((ext_vector_type(4)));
typedef float    floatv4 __attribute__((ext_vector_type(4)));

#define C_DIM 256
#define K_CODES 1024
#define HW 1024
#define NPIX 32768
#define USTR 520          // padded unit stride in f16 (512 data + 8 pad)

#define GLOAD_LDS16(g, l) __builtin_amdgcn_global_load_lds(                    \
    (const __attribute__((address_space(1))) unsigned int*)(g),                \
    (__attribute__((address_space(3))) unsigned int*)(l), 16, 0, 0)

// ---------------- kernel 1: normalize codebook + scaled f16 split -----------
__global__ __launch_bounds__(256) void vq_norm_w(const float* __restrict__ w,
                                                 float* __restrict__ w_nT,
                                                 _Float16* __restrict__ wh,
                                                 _Float16* __restrict__ wl) {
    const int row = blockIdx.x;        // 0..1023
    const int t   = threadIdx.x;       // 0..255
    float x = w[row * C_DIM + t];
    float s = x * x;
    #pragma unroll
    for (int off = 32; off > 0; off >>= 1) s += __shfl_down(s, off, 64);
    __shared__ float wsum[4];
    if ((t & 63) == 0) wsum[t >> 6] = s;
    __syncthreads();
    float tot = wsum[0] + wsum[1] + wsum[2] + wsum[3];
    float inv = 1.0f / fmaxf(sqrtf(tot), 1e-12f);
    float y = x * inv;
    w_nT[t * K_CODES + row] = y;       // transposed for finalize's L1-row gather
    float ys = 16.0f * y;
    _Float16 hi = (_Float16)ys;
    wh[row * C_DIM + t] = hi;
    wl[row * C_DIM + t] = (_Float16)(ys - (float)hi);
}

// ---------------- kernel 2: fused split + MFMA GEMM + argmax ----------------
// grid (256 m-tiles, 8 n-tiles), 256 thr = 4 waves 2x2; wave tile 64x64.
// BK=32, 8 phases. A: z fp32 -> reg split -> ds_write_b64 frag-order.
//                  B: global_load_lds frag-order DMA (4 units/wave, 2 planes).
__global__ __launch_bounds__(256, 4) void vq_gemm(
        const float* __restrict__ z,
        const _Float16* __restrict__ wh, const _Float16* __restrict__ wl,
        float* __restrict__ cand_val, int* __restrict__ cand_idx) {
    __shared__ _Float16 Ah[8 * USTR], Al[8 * USTR];   // 8.3 KB each
    __shared__ _Float16 Bh[8 * USTR], Bl[8 * USTR];
    __shared__ float red_v[128][2];
    __shared__ int   red_i[128][2];

    const int tid  = threadIdx.x;
    const int lane = tid & 63, wave = tid >> 6;
    const int wm = wave >> 1, wn = wave & 1;
    const int quad = lane >> 4, l15 = lane & 15;
    const int m0 = blockIdx.x * 128, n0 = blockIdx.y * 128;
    const int b  = m0 >> 10, p0 = m0 & 1023;

    // ---- B DMA setup: wave w stages 4 units; planes: w0,w1->Bh  w2,w3->Bl
    const _Float16* bsrc = (wave < 2) ? wh : wl;
    _Float16*       bdst = (wave < 2) ? Bh : Bl;
    const int ub = (wave & 1) * 4;                 // unit base within plane
    const _Float16* gB[4];
    _Float16*       lB[4];
    #pragma unroll
    for (int i = 0; i < 4; i++) {
        gB[i] = bsrc + (size_t)(n0 + (ub + i) * 16 + l15) * C_DIM + quad * 8;
        lB[i] = bdst + (ub + i) * USTR;
    }

    // ---- A stage setup: wave = k-quad; lane -> (pixel group, k-subgroup)
    const int ap = (lane & 31) * 4;                // local pixel base 0..124
    const int as = lane >> 5;                      // k sub (0,1) -> j base as*4
    const int ak = wave * 8 + as * 4;              // k rel in [0,32)
    const float* zA = z + ((size_t)b * C_DIM + ak) * HW + p0 + ap;

    floatx4 acc[4][4];
    #pragma unroll
    for (int i = 0; i < 4; i++)
        #pragma unroll
        for (int j = 0; j < 4; j++) acc[i][j] = (floatx4){0.f, 0.f, 0.f, 0.f};

    const int afrag = wm * 4, bfrag = wn * 4;

    for (int kt = 0; kt < 8; kt++) {
        __syncthreads();                 // prior iter's frag reads done
        // B DMA (in flight during A load+split below)
        #pragma unroll
        for (int i = 0; i < 4; i++)
            GLOAD_LDS16(gB[i] + kt * 32, lB[i]);
        // A: load 4 rows x 4 pixels fp32, split, write frag-order
        floatv4 za[4];
        #pragma unroll
        for (int r = 0; r < 4; r++)
            za[r] = *(const floatv4*)(zA + (size_t)(kt * 32 + r) * HW);
        #pragma unroll
        for (int i = 0; i < 4; i++) {
            half4 hv, lv;
            #pragma unroll
            for (int r = 0; r < 4; r++) {
                float xv = 4.0f * za[r][i];
                _Float16 h = (_Float16)xv;
                hv[r] = h;
                lv[r] = (_Float16)(xv - (float)h);
            }
            const int p = ap + i;
            const int aidx = (p >> 4) * USTR + wave * 128 + (p & 15) * 8 + as * 4;
            *(half4*)&Ah[aidx] = hv;
            *(half4*)&Al[aidx] = lv;
        }
        __syncthreads();                 // drains vmcnt (B DMA) + lgkm (A writes)

        half8 ah[4], al[4], bh[4], bl[4];
        #pragma unroll
        for (int i = 0; i < 4; i++) {
            ah[i] = *(const half8*)&Ah[(afrag + i) * USTR + lane * 8];
            al[i] = *(const half8*)&Al[(afrag + i) * USTR + lane * 8];
            bh[i] = *(const half8*)&Bh[(bfrag + i) * USTR + lane * 8];
            bl[i] = *(const half8*)&Bl[(bfrag + i) * USTR + lane * 8];
        }
        #pragma unroll
        for (int mi = 0; mi < 4; mi++)
            #pragma unroll
            for (int ni = 0; ni < 4; ni++) {
                acc[mi][ni] = __builtin_amdgcn_mfma_f32_16x16x32_f16(ah[mi], bh[ni], acc[mi][ni], 0, 0, 0);
                acc[mi][ni] = __builtin_amdgcn_mfma_f32_16x16x32_f16(ah[mi], bl[ni], acc[mi][ni], 0, 0, 0);
                acc[mi][ni] = __builtin_amdgcn_mfma_f32_16x16x32_f16(al[mi], bh[ni], acc[mi][ni], 0, 0, 0);
            }
    }

    // epilogue: per-lane best over ni, shfl-reduce over quad's 16 lanes
    #pragma unroll
    for (int mi = 0; mi < 4; mi++) {
        #pragma unroll
        for (int r = 0; r < 4; r++) {
            float bv = -__builtin_inff();
            int   bi = 0x7fffffff;
            #pragma unroll
            for (int ni = 0; ni < 4; ni++) {
                float v = acc[mi][ni][r];
                int  ci = n0 + wn * 64 + ni * 16 + l15;
                if (v > bv || (v == bv && ci < bi)) { bv = v; bi = ci; }
            }
            #pragma unroll
            for (int mk = 8; mk; mk >>= 1) {
                float ov = __shfl_xor(bv, mk, 16);
                int   oi = __shfl_xor(bi, mk, 16);
                if (ov > bv || (ov == bv && oi < bi)) { bv = ov; bi = oi; }
            }
            if (l15 == 0) {
                int row = wm * 64 + mi * 16 + quad * 4 + r;  // C/D: row=(lane>>4)*4+reg
                red_v[row][wn] = bv;
                red_i[row][wn] = bi;
            }
        }
    }
    __syncthreads();
    if (tid < 128) {
        float bv = red_v[tid][0]; int bi = red_i[tid][0];
        float v2 = red_v[tid][1]; int i2 = red_i[tid][1];
        if (v2 > bv || (v2 == bv && i2 < bi)) { bv = v2; bi = i2; }
        const int pix = m0 + tid;
        cand_val[(size_t)pix * 8 + blockIdx.y] = bv;
        cand_idx[(size_t)pix * 8 + blockIdx.y] = bi;
    }
}

// ---------------- kernel 3: reduce candidates + coalesced gather ------------
// grid (32 batches, 8 channel-groups), 256 thr. Coalesced 1KB z_q stores;
// codebook gathered from w_nT so each c-iteration hits one 4KB L1-resident row.
__global__ __launch_bounds__(256) void vq_finalize(
        const float* __restrict__ cand_val,
        const int*   __restrict__ cand_idx,
        const float* __restrict__ w_nT,  // [256][1024]
        float* __restrict__ zq,          // [32][256][1024]
        float* __restrict__ idx_out) {   // [32768] as float
    __shared__ int idx_s[1024];
    const int t  = threadIdx.x;
    const int b  = blockIdx.x;
    const int cg = blockIdx.y;           // channels cg*32 .. +31
    #pragma unroll
    for (int q = 0; q < 4; q++) {
        const int p = q * 256 + t;
        const int n = b * 1024 + p;
        const size_t base = (size_t)n * 8;
        float bv = cand_val[base]; int bi = cand_idx[base];
        #pragma unroll
        for (int j = 1; j < 8; j++) {
            float v = cand_val[base + j];
            int   c = cand_idx[base + j];
            if (v > bv || (v == bv && c < bi)) { bv = v; bi = c; }
        }
        idx_s[p] = bi;
        if (cg == 0) idx_out[n] = (float)bi;
    }
    __syncthreads();
    float* zqb = zq + (size_t)b * (C_DIM * HW);
    for (int c = 0; c < 32; c++) {
        const int ch = cg * 32 + c;
        const float* wrow = w_nT + (size_t)ch * K_CODES;
        #pragma unroll
        for (int q = 0; q < 4; q++) {
            const int p = q * 256 + t;
            zqb[(size_t)ch * HW + p] = wrow[idx_s[p]];
        }
    }
}

// ---------------- launcher --------------------------------------------------
extern "C" void kernel_launch(void* const* d_in, const int* in_sizes, int n_in,
                              void* d_out, int out_size, void* d_ws, size_t ws_size,
                              hipStream_t stream) {
    const float* z = (const float*)d_in[0];   // 32*256*32*32
    const float* w = (const float*)d_in[1];   // 1024*256
    float* out     = (float*)d_out;           // z_q (8388608) ++ indices (32768)

    char* ws = (char*)d_ws;
    float*    w_nT = (float*)(ws);                       //  0    .. 1 MB
    _Float16* wh   = (_Float16*)(ws + (1u << 20));       //  1 MB .. 1.5 MB
    _Float16* wl   = (_Float16*)(ws + (3u << 19));       //  1.5  .. 2 MB
    float*    cval = (float*)(ws + (2u << 20));          //  2 MB .. 3 MB
    int*      cidx = (int*)(ws + (3u << 20));            //  3 MB .. 4 MB

    vq_norm_w<<<K_CODES, 256, 0, stream>>>(w, w_nT, wh, wl);
    vq_gemm<<<dim3(NPIX / 128, K_CODES / 128), 256, 0, stream>>>(z, wh, wl, cval, cidx);
    vq_finalize<<<dim3(32, 8), 256, 0, stream>>>(cval, cidx, w_nT, out, out + 8388608);
}